// Round 1
// baseline (558.555 us; speedup 1.0000x reference)
//
#include <hip/hip_runtime.h>

#define BB  2
#define NN  100000
#define MM  16384
#define SS  3
#define EE  262144
#define CC  32     // COUT
#define HH  64     // HID
#define RR  32     // latent rows per block
#define TPB 256

// gelu (tanh approximation, matches jax.nn.gelu approximate=True)
__device__ __forceinline__ float gelu_tanh(float x){
  float u  = 0.7978845608028654f * fmaf(0.044715f * x, x * x, x); // sqrt(2/pi)*(x+0.044715x^3)
  float e  = __expf(2.0f * u);
  float r  = __builtin_amdgcn_rcpf(e + 1.0f);   // 1/(e^{2u}+1)
  // tanh(u) = 1 - 2r ; gelu = 0.5*x*(1+tanh) = x*(1-r)
  return x * (1.0f - r);
}

extern "C" __global__ void __launch_bounds__(TPB)
magno_main(const float* __restrict__ x_coord,
           const float* __restrict__ pndata,
           const float* __restrict__ lat,
           const int*   __restrict__ nbr_idx,
           const int*   __restrict__ row_idx,
           const float* __restrict__ W_lift,
           const float* __restrict__ b_lift,
           const float* __restrict__ W1,
           const float* __restrict__ b1,
           const float* __restrict__ W2,
           const float* __restrict__ b2,
           const float* __restrict__ W3,
           const float* __restrict__ b3,
           const float* __restrict__ Ws1,
           const float* __restrict__ bs1,
           const float* __restrict__ Ws2,
           const float* __restrict__ bs2,
           float* __restrict__ out)
{
  const int blocksPerBatch = MM / RR;            // 512
  const int b   = blockIdx.x / blocksPerBatch;
  const int m0  = (blockIdx.x % blocksPerBatch) * RR;
  const int tid = threadIdx.x;

  __shared__ __align__(16) float vsh[RR * 68];   // lat part of layer1, padded stride 68
  __shared__ float acc [RR * CC];
  __shared__ float outc[RR * CC];
  __shared__ float swsh[RR * 4];                 // scale weights per row
  __shared__ float cnt [RR];

  // ---- per-block precompute: v[row] = lat@W1[:,2:4] + b1, and scale softmax weights ----
  for (int idx = tid; idx < RR * HH; idx += TPB){
    int r = idx >> 6, j = idx & 63;
    float l0 = lat[(m0 + r) * 2 + 0];
    float l1 = lat[(m0 + r) * 2 + 1];
    vsh[r * 68 + j] = fmaf(l0, W1[j * 4 + 2], fmaf(l1, W1[j * 4 + 3], b1[j]));
  }
  if (tid < RR){
    int m = m0 + tid;
    float l0 = lat[m * 2 + 0], l1 = lat[m * 2 + 1];
    float t[16];
    #pragma unroll
    for (int i = 0; i < 16; i++)
      t[i] = fmaxf(fmaf(l0, Ws1[i * 2 + 0], fmaf(l1, Ws1[i * 2 + 1], bs1[i])), 0.0f);
    float a0 = bs2[0], a1 = bs2[1], a2 = bs2[2];
    #pragma unroll
    for (int i = 0; i < 16; i++){
      a0 = fmaf(t[i], Ws2[0 * 16 + i], a0);
      a1 = fmaf(t[i], Ws2[1 * 16 + i], a1);
      a2 = fmaf(t[i], Ws2[2 * 16 + i], a2);
    }
    float mx = fmaxf(a0, fmaxf(a1, a2));
    float e0 = __expf(a0 - mx), e1 = __expf(a1 - mx), e2 = __expf(a2 - mx);
    float inv = 1.0f / (e0 + e1 + e2);
    swsh[tid * 4 + 0] = e0 * inv;
    swsh[tid * 4 + 1] = e1 * inv;
    swsh[tid * 4 + 2] = e2 * inv;
  }
  for (int idx = tid; idx < RR * CC; idx += TPB) outc[idx] = 0.0f;

  // ---- per-scale edge processing ----
  for (int s = 0; s < SS; s++){
    __syncthreads();
    for (int idx = tid; idx < RR * CC; idx += TPB) acc[idx] = 0.0f;
    if (tid < RR) cnt[tid] = 0.0f;
    __syncthreads();

    const int* rows = row_idx + (size_t)(b * SS + s) * EE;
    const int* nbrs = nbr_idx + (size_t)(b * SS + s) * EE;

    // binary search edge range [e0, e1) for rows in [m0, m0+RR)
    int lo = 0, hi = EE;
    while (lo < hi){ int mid = (lo + hi) >> 1; if (rows[mid] < m0) lo = mid + 1; else hi = mid; }
    const int eb = lo;
    lo = eb; hi = EE;
    while (lo < hi){ int mid = (lo + hi) >> 1; if (rows[mid] < m0 + RR) lo = mid + 1; else hi = mid; }
    const int ee = lo;

    for (int e = eb + tid; e < ee; e += TPB){
      const int row = rows[e] - m0;
      const int nbr = nbrs[e];
      const float2 xc = *(const float2*)&x_coord[((size_t)b * NN + nbr) * 2];

      // layer 1: h1 = gelu(x0*W1[:,0] + x1*W1[:,1] + v[row])
      float h1[HH];
      const float4* vr = (const float4*)&vsh[row * 68];
      #pragma unroll
      for (int jq = 0; jq < 16; jq++){
        float4 vv = vr[jq];
        h1[jq*4+0] = gelu_tanh(fmaf(xc.x, W1[(jq*4+0)*4+0], fmaf(xc.y, W1[(jq*4+0)*4+1], vv.x)));
        h1[jq*4+1] = gelu_tanh(fmaf(xc.x, W1[(jq*4+1)*4+0], fmaf(xc.y, W1[(jq*4+1)*4+1], vv.y)));
        h1[jq*4+2] = gelu_tanh(fmaf(xc.x, W1[(jq*4+2)*4+0], fmaf(xc.y, W1[(jq*4+2)*4+1], vv.z)));
        h1[jq*4+3] = gelu_tanh(fmaf(xc.x, W1[(jq*4+3)*4+0], fmaf(xc.y, W1[(jq*4+3)*4+1], vv.w)));
      }

      // layer 2: h2 = gelu(h1 @ W2.T + b2) — W2 rows via wave-uniform scalar loads
      float h2[HH];
      #pragma unroll 4
      for (int j = 0; j < HH; j++){
        const float* w2r = &W2[j * HH];
        float t0 = 0.f, t1 = 0.f, t2 = 0.f, t3 = 0.f;
        #pragma unroll
        for (int k = 0; k < HH; k += 4){
          t0 = fmaf(h1[k+0], w2r[k+0], t0);
          t1 = fmaf(h1[k+1], w2r[k+1], t1);
          t2 = fmaf(h1[k+2], w2r[k+2], t2);
          t3 = fmaf(h1[k+3], w2r[k+3], t3);
        }
        h2[j] = gelu_tanh(b2[j] + ((t0 + t1) + (t2 + t3)));
      }

      // lift (on the fly) + layer 3 + LDS accumulate
      const float p0 = pndata[((size_t)b * NN + nbr) * 3 + 0];
      const float p1 = pndata[((size_t)b * NN + nbr) * 3 + 1];
      const float p2 = pndata[((size_t)b * NN + nbr) * 3 + 2];
      #pragma unroll 2
      for (int c = 0; c < CC; c++){
        const float* w3r = &W3[c * HH];
        float t0 = 0.f, t1 = 0.f, t2 = 0.f, t3 = 0.f;
        #pragma unroll
        for (int k = 0; k < HH; k += 4){
          t0 = fmaf(h2[k+0], w3r[k+0], t0);
          t1 = fmaf(h2[k+1], w3r[k+1], t1);
          t2 = fmaf(h2[k+2], w3r[k+2], t2);
          t3 = fmaf(h2[k+3], w3r[k+3], t3);
        }
        float kv = b3[c] + ((t0 + t1) + (t2 + t3));
        float pv = fmaf(p0, W_lift[c*3+0], fmaf(p1, W_lift[c*3+1], fmaf(p2, W_lift[c*3+2], b_lift[c])));
        atomicAdd(&acc[row * CC + c], kv * pv);
      }
      atomicAdd(&cnt[row], 1.0f);
    }

    __syncthreads();
    // outc += sw[m,s] * acc/max(cnt,1)
    for (int idx = tid; idx < RR * CC; idx += TPB){
      int r = idx >> 5;
      outc[idx] = fmaf(swsh[r * 4 + s], acc[idx] / fmaxf(cnt[r], 1.0f), outc[idx]);
    }
  }

  __syncthreads();
  float* ob = out + ((size_t)b * MM + m0) * CC;
  for (int idx = tid; idx < RR * CC; idx += TPB) ob[idx] = outc[idx];
}

extern "C" void kernel_launch(void* const* d_in, const int* in_sizes, int n_in,
                              void* d_out, int out_size, void* d_ws, size_t ws_size,
                              hipStream_t stream)
{
  const float* x_coord = (const float*)d_in[0];
  const float* pndata  = (const float*)d_in[1];
  const float* lat     = (const float*)d_in[2];
  const int*   nbr_idx = (const int*)d_in[3];
  const int*   row_idx = (const int*)d_in[4];
  const float* W_lift  = (const float*)d_in[5];
  const float* b_lift  = (const float*)d_in[6];
  const float* W1      = (const float*)d_in[7];
  const float* b1      = (const float*)d_in[8];
  const float* W2      = (const float*)d_in[9];
  const float* b2      = (const float*)d_in[10];
  const float* W3      = (const float*)d_in[11];
  const float* b3      = (const float*)d_in[12];
  const float* Ws1     = (const float*)d_in[13];
  const float* bs1     = (const float*)d_in[14];
  const float* Ws2     = (const float*)d_in[15];
  const float* bs2     = (const float*)d_in[16];
  float* out = (float*)d_out;

  dim3 grid(BB * (MM / RR));
  dim3 block(TPB);
  hipLaunchKernelGGL(magno_main, grid, block, 0, stream,
                     x_coord, pndata, lat, nbr_idx, row_idx,
                     W_lift, b_lift, W1, b1, W2, b2, W3, b3,
                     Ws1, bs1, Ws2, bs2, out);
}